// Round 16
// baseline (723.919 us; speedup 1.0000x reference)
//
#include <hip/hip_runtime.h>
#include <hip/hip_bf16.h>
#include <math.h>

typedef __attribute__((ext_vector_type(4))) float f4;
typedef __attribute__((ext_vector_type(4))) float f32x4;
typedef __attribute__((ext_vector_type(8))) short bf16x8;

#define HSZ 128
#define WSZ 128
#define HW 16384

__device__ __forceinline__ float sigm(float x){ return 1.f/(1.f+__expf(-x)); }
__device__ __forceinline__ float tanh_fast(float x){ return 1.f - 2.f/(1.f+__expf(2.f*x)); }
__device__ __forceinline__ float bf_lo(unsigned u){ return __uint_as_float(u<<16); }
__device__ __forceinline__ float bf_hi(unsigned u){ return __uint_as_float(u & 0xffff0000u); }

// ---------------- setup: conv weights -> bf16 [dy][ck][dx][256 oc][32 k]; WhB bf16 [192][64] ----
__global__ void k_setup(const float* __restrict__ conv_w, const float* __restrict__ m_w,
                        __hip_bfloat16* __restrict__ wB, __hip_bfloat16* __restrict__ WhB){
  int idx = blockIdx.x*256 + threadIdx.x;
  if (idx < 294912){
    int kk = idx & 31;
    int oc = (idx>>5) & 255;
    int q  = idx >> 13;              // (dy*4+ck)*3+dx
    int dx = q % 3; int t2 = q / 3; int ck = t2 & 3; int dy = t2 >> 2;
    int ic = ck*32 + kk;
    wB[idx] = __float2bfloat16(conv_w[((oc*128+ic)*3+dy)*3+dx]);
  } else if (idx < 294912 + 12288){
    int j = idx - 294912;
    int o = j >> 6, ci = j & 63;
    WhB[j] = __float2bfloat16(m_w[o*192 + 128 + ci]);
  }
}

// W2[o*128+zi] = sum_zo m_w[o*192+zo]*z_w[zo*128+zi];  bc[o] = m_w[o,:128]@z_b + m_b
__global__ void k_w2(const float* __restrict__ m_w, const float* __restrict__ z_w,
                     const float* __restrict__ z_b, const float* __restrict__ m_b,
                     float* __restrict__ W2, float* __restrict__ bc){
  int idx = blockIdx.x*256 + threadIdx.x;
  if (idx < 24576){
    int o = idx >> 7, zi = idx & 127;
    float s = 0.f;
    for (int zo=0; zo<128; zo++) s += m_w[o*192+zo]*z_w[zo*128+zi];
    W2[idx] = s;
  } else if (idx < 24576 + 192){
    int o = idx - 24576;
    float s = m_b[o];
    for (int zo=0; zo<128; zo++) s += m_w[o*192+zo]*z_b[zo];
    bc[o] = s;
  }
}

// ---------------- im pre-pass: [b][c][y][x] f32 (x,h) -> [bl][y][x][128ch] bf16 ----
__global__ __launch_bounds__(256) void k_im(const float* __restrict__ x,
    const float* __restrict__ h, __hip_bfloat16* __restrict__ im, int b0){
  __shared__ __hip_bfloat16 T[128*136];
  int bid = blockIdx.x; int y = bid & 127, bl = bid >> 7; int b = b0 + bl;
  int t = threadIdx.x;
  for (int idx=t; idx<4096; idx+=256){
    int c = idx>>5, xq = idx&31;
    const float* src = (c<64)? x : h; int cm = c&63;
    f4 v = *(const f4*)(src + ((((size_t)b*64+cm)*HSZ + y)*WSZ + xq*4));
    #pragma unroll
    for (int j=0;j<4;j++) T[(xq*4+j)*136 + c] = __float2bfloat16(v[j]);
  }
  __syncthreads();
  for (int idx=t; idx<2048; idx+=256){
    int xx = idx>>4, q = idx&15;
    uint4 v = *(const uint4*)&T[xx*136 + q*8];
    *(uint4*)(im + ((((size_t)bl*HSZ + y)*WSZ + xx)*128 + q*8)) = v;
  }
}

// ---------------- conv3x3 implicit-GEMM MFMA v11: 512 thr, acc[4][2] ----------------
// 1-row tile, input-only dbuf LDS (pad-40), weights direct from global.
// 8 waves: wave w -> oc-half (w&1)*64, px-quarter (w>>1)*32. acc = 32 AGPR/thread
// -> ~82 total regs -> up to 6 waves/SIMD (was 3 at 140 regs).
__global__ __launch_bounds__(512, 4) void k_conv(const __hip_bfloat16* __restrict__ im,
    const __hip_bfloat16* __restrict__ wB, __hip_bfloat16* __restrict__ cc, int b0){
  __shared__ __align__(16) short LDS[10560];           // 21,120 B (OutL[64][136]=17,408 fits)
  short* buf0 = LDS;                                   // [132][40]
  short* buf1 = LDS + 5280;
  int bid = blockIdx.x;
  int y = bid & 127, bl = bid >> 7; int b = b0 + bl;
  int oc0 = blockIdx.y * 128;
  int t = threadIdx.x;
  int lane = t & 63, w = t >> 6;                       // w in 0..7
  int ln15 = lane & 15, h8 = (lane>>4)*8;
  int och = (w&1)*64, pxq = (w>>1)*32;
  int px0 = t>>2, q0 = t&3;                            // staging: 512 thr cover px 0..127

  f32x4 acc[4][2];
  #pragma unroll
  for (int mi=0;mi<4;mi++)
    #pragma unroll
    for (int ni=0;ni<2;ni++) acc[mi][ni] = (f32x4){0.f,0.f,0.f,0.f};

  auto stage = [&](int s, short* dst){
    int dy = s>>2, ck = s&3;
    int yy = y + dy - 1;
    bool yok = (yy>=0) && (yy<HSZ);
    const __hip_bfloat16* rb = im + (((size_t)bl*HSZ + yy)*WSZ)*128 + ck*32;
    uint4 v0 = make_uint4(0u,0u,0u,0u);
    uint4 v2 = make_uint4(0u,0u,0u,0u);
    if (yok && px0>=1)       v0 = *(const uint4*)(rb + (size_t)(px0-1)*128 + q0*8);
    if (yok && t<4)          v2 = *(const uint4*)(rb + (size_t)127*128 + q0*8);   // px=128
    *(uint4*)&dst[px0*40 + q0*8] = v0;
    if (t<16) *(uint4*)&dst[(128+(t>>2))*40 + q0*8] = v2;                         // px 128..131
  };
  auto compute = [&](int s, const short* src){
    #pragma unroll
    for (int dx=0; dx<3; dx++){
      const __hip_bfloat16* wp = wB + (((size_t)(s*3+dx)*256 + oc0 + och + ln15)*32 + h8);
      bf16x8 af[4], bfr[2];
      #pragma unroll
      for (int i=0;i<4;i++) af[i]  = *(const bf16x8*)(wp + (size_t)i*16*32);
      #pragma unroll
      for (int n=0;n<2;n++) bfr[n] = *(const bf16x8*)&src[(pxq + n*16 + ln15 + dx)*40 + h8];
      #pragma unroll
      for (int mi=0;mi<4;mi++)
        #pragma unroll
        for (int ni=0;ni<2;ni++)
          acc[mi][ni] = __builtin_amdgcn_mfma_f32_16x16x32_bf16(af[mi], bfr[ni], acc[mi][ni], 0, 0, 0);
    }
  };

  stage(0, buf0);
  __syncthreads();
  for (int s=0; s<12; s++){
    short* cur = (s&1)? buf1 : buf0;
    short* nxt = (s&1)? buf0 : buf1;
    if (s < 11) stage(s+1, nxt);
    compute(s, cur);
    __syncthreads();
  }

  // epilogue: two 64-oc passes through OutL[64][136]; waves (w&1)==p write pass p
  __hip_bfloat16* OutL = (__hip_bfloat16*)LDS;
  int hv4 = (lane>>4)*4;
  for (int p=0; p<2; p++){
    if ((w&1) == p){
      #pragma unroll
      for (int mi=0;mi<4;mi++)
        #pragma unroll
        for (int ni=0;ni<2;ni++){
          #pragma unroll
          for (int r=0;r<4;r++)
            OutL[(mi*16 + hv4 + r)*136 + pxq + ni*16 + ln15] = __float2bfloat16(acc[mi][ni][r]);
        }
    }
    __syncthreads();
    for (int idx=t; idx<1024; idx+=512){
      int oc = idx>>4, qc = idx&15;
      uint4 v = *(const uint4*)&OutL[oc*136 + qc*8];
      *(uint4*)(cc + ((((size_t)b*256 + oc0 + p*64 + oc)*HSZ + y)*WSZ + qc*8)) = v;
    }
    __syncthreads();
  }
}

// ---------------- instance-norm stats -> per-(b,ch) scale/shift ----------------
__global__ __launch_bounds__(256) void k_gnstats(const __hip_bfloat16* __restrict__ cc,
    const float* __restrict__ gn_w, const float* __restrict__ gn_b,
    float* __restrict__ scale, float* __restrict__ shift){
  int bc_ = blockIdx.x;                           // b*256+oc
  const uint4* p = (const uint4*)(cc + (size_t)bc_*HW);
  float s=0.f, ss=0.f;
  for (int ch=threadIdx.x; ch<2048; ch+=256){
    uint4 u = p[ch];
    unsigned uw[4] = {u.x, u.y, u.z, u.w};
    #pragma unroll
    for (int w=0; w<4; w++){
      float a = bf_lo(uw[w]);
      float b2 = bf_hi(uw[w]);
      s += a + b2; ss += a*a + b2*b2;
    }
  }
  for (int off=1; off<64; off<<=1){ s += __shfl_xor(s, off); ss += __shfl_xor(ss, off); }
  __shared__ float rs_[4], rss_[4];
  int wv = threadIdx.x>>6, ln = threadIdx.x&63;
  if (ln==0){ rs_[wv]=s; rss_[wv]=ss; }
  __syncthreads();
  if (threadIdx.x==0){
    float S = rs_[0]+rs_[1]+rs_[2]+rs_[3];
    float SS = rss_[0]+rss_[1]+rss_[2]+rss_[3];
    float mu = S*(1.f/16384.f);
    float var = SS*(1.f/16384.f) - mu*mu;
    float r = rsqrtf(var + 1e-5f);
    int oc = bc_ & 255;
    float sc = gn_w[oc]*r;
    scale[bc_] = sc;
    shift[bc_] = gn_b[oc] - mu*sc;
  }
}

// ---------------- LSTM gating: c_next + h_next + fused h-pool ----------------
__global__ __launch_bounds__(256) void k_gate(const __hip_bfloat16* __restrict__ cc,
    const float* __restrict__ cin, const float* __restrict__ scale, const float* __restrict__ shift,
    float* __restrict__ out_c, float* __restrict__ out_h, float* __restrict__ poolh){
  int bid = blockIdx.x;                 // b*64+c
  int b = bid>>6, c = bid&63;
  size_t base_i = ((size_t)b*256 + c)*HW;
  const uint4* pi = (const uint4*)(cc + base_i);
  const uint4* pf = (const uint4*)(cc + base_i + (size_t)64*HW);
  const uint4* pg = (const uint4*)(cc + base_i + (size_t)128*HW);
  const uint4* po = (const uint4*)(cc + base_i + (size_t)192*HW);
  float ssi = scale[b*256+c],     shi = shift[b*256+c];
  float ssf = scale[b*256+64+c],  shf = shift[b*256+64+c];
  float ssg = scale[b*256+128+c], shg = shift[b*256+128+c];
  float sso = scale[b*256+192+c], sho = shift[b*256+192+c];
  size_t pbase = ((size_t)b*64 + c)*HW;
  const f4* pc_ = (const f4*)(cin + pbase);
  f4* oc_ = (f4*)(out_c + pbase);
  f4* oh_ = (f4*)(out_h + pbase);
  int lane = threadIdx.x & 63;
  for (int ch = threadIdx.x; ch < 2048; ch += 256){
    uint4 ui = pi[ch], uf = pf[ch], ug = pg[ch], uo = po[ch];
    unsigned iu[4]={ui.x,ui.y,ui.z,ui.w}, fu[4]={uf.x,uf.y,uf.z,uf.w};
    unsigned gu[4]={ug.x,ug.y,ug.z,ug.w}, ou[4]={uo.x,uo.y,uo.z,uo.w};
    f4 ca = pc_[ch*2], cb = pc_[ch*2+1];
    float cvv[8] = {ca[0],ca[1],ca[2],ca[3],cb[0],cb[1],cb[2],cb[3]};
    float rc[8], rh[8];
    #pragma unroll
    for (int w=0; w<4; w++){
      #pragma unroll
      for (int hl=0; hl<2; hl++){
        int k = w*2+hl;
        float iv = (hl? bf_hi(iu[w]) : bf_lo(iu[w]))*ssi + shi;
        float fv = (hl? bf_hi(fu[w]) : bf_lo(fu[w]))*ssf + shf;
        float gv = (hl? bf_hi(gu[w]) : bf_lo(gu[w]))*ssg + shg;
        float ov = (hl? bf_hi(ou[w]) : bf_lo(ou[w]))*sso + sho;
        float cn = sigm(fv)*cvv[k] + sigm(iv)*tanh_fast(gv);
        rc[k] = cn;
        rh[k] = sigm(ov)*tanh_fast(cn);
      }
    }
    f4 o0 = {rc[0],rc[1],rc[2],rc[3]}, o1 = {rc[4],rc[5],rc[6],rc[7]};
    f4 h0 = {rh[0],rh[1],rh[2],rh[3]}, h1 = {rh[4],rh[5],rh[6],rh[7]};
    oc_[ch*2] = o0; oc_[ch*2+1] = o1;
    oh_[ch*2] = h0; oh_[ch*2+1] = h1;
    float ps = ((rh[0]+rh[1])+(rh[2]+rh[3])) + ((rh[4]+rh[5])+(rh[6]+rh[7]));
    ps += __shfl_xor(ps, 1);
    ps += __shfl_xor(ps, 2);
    ps += __shfl_xor(ps, 4);
    if ((lane & 7) == 0) poolh[(size_t)bid*256 + (ch>>3)] = ps*(1.f/64.f);
  }
}

// ---------------- pooling of m only: (B,64,HW) -> (B,64,256) ----------------
__global__ __launch_bounds__(256) void k_poolm(const float* __restrict__ m_in,
    float* __restrict__ poolm){
  int pc = blockIdx.x;                  // b*64+c
  const float* src = m_in + (size_t)pc*HW;
  float* dst = poolm + (size_t)pc*256;
  int n = threadIdx.x;                  // token
  const f4* p = (const f4*)(src + n*64);
  float s = 0.f;
  #pragma unroll
  for (int i=0;i<16;i++){ f4 v = p[i]; s += (v[0]+v[1]) + (v[2]+v[3]); }
  dst[n] = s*(1.f/64.f);
}

// ---------------- 5 pooled projections ----------------
__global__ __launch_bounds__(256) void k_proj(const float* __restrict__ pool,
    const float* qw,const float* qb,const float* kw,const float* kb,
    const float* vw,const float* vb,const float* kmw,const float* kmb,
    const float* vmw,const float* vmb, float* __restrict__ proj){
  int bid = blockIdx.x;  // b*5+p
  int p = bid % 5, b = bid / 5;
  const float* P = pool + (p>=3? 262144:0) + (size_t)b*16384;
  const float* W; const float* Bs;
  if (p==0){W=qw;Bs=qb;} else if(p==1){W=kw;Bs=kb;} else if(p==2){W=vw;Bs=vb;}
  else if (p==3){W=kmw;Bs=kmb;} else {W=vmw;Bs=vmb;}
  int n = threadIdx.x;
  float acc[64];
  #pragma unroll
  for (int o=0;o<64;o++) acc[o]=0.f;
  for (int c=0;c<64;c++){
    float pv = P[c*256+n];
    #pragma unroll
    for (int o=0;o<64;o++) acc[o] += W[o*64+c]*pv;
  }
  float* dst = proj + (size_t)p*262144 + (size_t)b*16384;
  #pragma unroll
  for (int o=0;o<64;o++) dst[o*256+n] = acc[o] + Bs[o];
}

// ---------------- attention scores + softmax ----------------
__global__ __launch_bounds__(256) void k_scores(const float* __restrict__ proj, float* __restrict__ A){
  int n = blockIdx.x, ty = blockIdx.y, b = blockIdx.z;
  const float* Q = proj + (size_t)b*16384;
  const float* K = proj + (size_t)(ty==0?1:3)*262144 + (size_t)b*16384;
  int mm = threadIdx.x;
  float s = 0.f;
  for (int c=0;c<64;c++) s += Q[c*256+n]*K[c*256+mm];
  float mx = s;
  for (int off=1; off<64; off<<=1) mx = fmaxf(mx, __shfl_xor(mx, off));
  __shared__ float r1[4], r2[4];
  int wv = threadIdx.x>>6, ln = threadIdx.x&63;
  if (ln==0) r1[wv]=mx;
  __syncthreads();
  mx = fmaxf(fmaxf(r1[0],r1[1]),fmaxf(r1[2],r1[3]));
  float e = __expf(s-mx);
  float sm = e;
  for (int off=1; off<64; off<<=1) sm += __shfl_xor(sm, off);
  if (ln==0) r2[wv]=sm;
  __syncthreads();
  sm = r2[0]+r2[1]+r2[2]+r2[3];
  A[(((size_t)ty*16+b)*256+n)*256+mm] = e/sm;
}

// ---------------- Z = V @ A^T (c-split for occupancy) ----------------
__global__ __launch_bounds__(256) void k_apply(const float* __restrict__ proj,
    const float* __restrict__ A, float* __restrict__ Zcat){
  int ty = blockIdx.x, b = blockIdx.y, cq = blockIdx.z;
  const float* V = proj + (size_t)(ty==0?2:4)*262144 + (size_t)b*16384 + (size_t)cq*16*256;
  const float* Ar = A + (((size_t)ty*16+b)*256 + threadIdx.x)*256;
  float acc[16];
  #pragma unroll
  for (int c=0;c<16;c++) acc[c]=0.f;
  for (int mm=0; mm<256; mm++){
    float a = Ar[mm];
    #pragma unroll
    for (int c=0;c<16;c++) acc[c] += V[c*256+mm]*a;
  }
  float* dst = Zcat + ((size_t)b*128 + ty*64 + cq*16)*256 + threadIdx.x;
  #pragma unroll
  for (int c=0;c<16;c++) dst[c*256] = acc[c];
}

// ---------------- Csmall = W2 @ [Zh;Zm] (192 x 256 per b), 32-out split ----------------
__global__ __launch_bounds__(256) void k_csmall(const float* __restrict__ Zcat,
    const float* __restrict__ W2, float* __restrict__ Cs){
  int oq = blockIdx.x, b = blockIdx.y;
  int o0 = oq*32;
  int n = threadIdx.x;
  float acc[32];
  #pragma unroll
  for (int o=0;o<32;o++) acc[o]=0.f;
  for (int zi=0; zi<128; zi++){
    float z = Zcat[((size_t)b*128+zi)*256 + n];
    #pragma unroll
    for (int o=0;o<32;o++) acc[o] += W2[(o0+o)*128 + zi]*z;
  }
  float* dst = Cs + ((size_t)b*192 + o0)*256 + n;
  #pragma unroll
  for (int o=0;o<32;o++) dst[o*256] = acc[o];
}

// ---------------- final: MFMA matvec + LDS-staged bilinear taps + gates ----------------
__global__ __launch_bounds__(256, 3) void k_final(
    const float* __restrict__ hn, const float* __restrict__ m_in,
    const __hip_bfloat16* __restrict__ WhB, const float* __restrict__ Cs,
    const float* __restrict__ bcv, float* __restrict__ out_h, float* __restrict__ out_m){
  __shared__ float rowF[64*69];          // [64 ch][64 px + pad5]
  __shared__ float CsL[192*36];          // [192 c'][2 rows x 16 + pad4]
  int bid = blockIdx.x;
  int xh = bid & 1, y = (bid>>1) & 127, b = bid >> 8;
  int x0 = xh*64;
  int t = threadIdx.x, lane = t & 63, w = t >> 6;
  int ln15 = lane & 15, hi = lane >> 4, h8 = hi*8;

  float sy = (y+0.5f)*0.125f - 0.5f;
  int iy = (int)floorf(sy); float fy = sy - (float)iy;
  int ya = min(max(iy,0),15), yb = min(max(iy+1,0),15);

  for (int idx=t; idx<1024; idx+=256){
    int c = idx>>4, xq = idx&15;
    f4 v = *(const f4*)(hn + ((((size_t)b*64+c)*HSZ + y)*WSZ + x0 + xq*4));
    float* d = &rowF[c*69 + xq*4];
    d[0]=v[0]; d[1]=v[1]; d[2]=v[2]; d[3]=v[3];
  }
  for (int idx=t; idx<1536; idx+=256){
    int cp = idx>>3, rr = (idx>>2)&1, q = idx&3;
    int ry = rr? yb : ya;
    f4 v = *(const f4*)(Cs + (((size_t)b*192 + cp)*256 + ry*16 + q*4));
    *(f4*)&CsL[cp*36 + rr*16 + q*4] = v;
  }
  __syncthreads();

  bf16x8 bfr[2];
  #pragma unroll
  for (int ks=0; ks<2; ks++){
    union { bf16x8 v; __hip_bfloat16 e[8]; } u;
    #pragma unroll
    for (int j=0;j<8;j++)
      u.e[j] = __float2bfloat16(rowF[(ks*32 + h8 + j)*69 + w*16 + ln15]);
    bfr[ks] = u.v;
  }
  f32x4 acc[12];
  #pragma unroll
  for (int mt=0;mt<12;mt++) acc[mt] = (f32x4){0.f,0.f,0.f,0.f};
  #pragma unroll
  for (int ks=0; ks<2; ks++){
    #pragma unroll
    for (int mt=0; mt<12; mt++){
      bf16x8 af = *(const bf16x8*)(WhB + ((mt*16+ln15)*64 + ks*32 + h8));
      acc[mt] = __builtin_amdgcn_mfma_f32_16x16x32_bf16(af, bfr[ks], acc[mt], 0, 0, 0);
    }
  }

  int xg = x0 + w*16 + ln15;
  float sx = (xg+0.5f)*0.125f - 0.5f;
  int ix = (int)floorf(sx); float fx = sx - (float)ix;
  int xa = min(max(ix,0),15), xb2 = min(max(ix+1,0),15);
  float w00=(1.f-fy)*(1.f-fx), w01=(1.f-fy)*fx, w10=fy*(1.f-fx), w11=fy*fx;
  int o00 = xa, o01 = xb2, o10 = 16+xa, o11 = 16+xb2;
  #pragma unroll
  for (int mt=0; mt<4; mt++){
    #pragma unroll
    for (int r=0; r<4; r++){
      int c = mt*16 + hi*4 + r;
      const float* p0 = &CsL[c*36];
      const float* p1 = &CsL[(64+c)*36];
      const float* p2 = &CsL[(128+c)*36];
      float vo = acc[mt][r]   + p0[o00]*w00 + p0[o01]*w01 + p0[o10]*w10 + p0[o11]*w11 + bcv[c];
      float vg = acc[mt+4][r] + p1[o00]*w00 + p1[o01]*w01 + p1[o10]*w10 + p1[o11]*w11 + bcv[64+c];
      float vi = acc[mt+8][r] + p2[o00]*w00 + p2[o01]*w01 + p2[o10]*w10 + p2[o11]*w11 + bcv[128+c];
      size_t pix = (((size_t)b*64+c)*HSZ + y)*WSZ + xg;
      float mv = m_in[pix];
      float smi = sigm(vi);
      float nm = (1.f-smi)*mv + smi*tanh_fast(vg);
      float nh = sigm(vo)*nm;
      out_h[pix] = nh;
      out_m[pix] = nm;
    }
  }
}

extern "C" void kernel_launch(void* const* d_in, const int* in_sizes, int n_in,
                              void* d_out, int out_size, void* d_ws, size_t ws_size,
                              hipStream_t stream){
  (void)in_sizes; (void)n_in; (void)out_size;
  const float* x    = (const float*)d_in[0];
  const float* cst  = (const float*)d_in[1];
  const float* h    = (const float*)d_in[2];
  const float* m    = (const float*)d_in[3];
  const float* conv_w = (const float*)d_in[4];
  // d_in[5] conv_b: exactly cancelled by instance norm — unused
  const float* gn_w = (const float*)d_in[6];
  const float* gn_b = (const float*)d_in[7];
  const float* qh_w = (const float*)d_in[8];  const float* qh_b = (const float*)d_in[9];
  const float* kh_w = (const float*)d_in[10]; const float* kh_b = (const float*)d_in[11];
  const float* vh_w = (const float*)d_in[12]; const float* vh_b = (const float*)d_in[13];
  const float* km_w = (const float*)d_in[14]; const float* km_b = (const float*)d_in[15];
  const float* vm_w = (const float*)d_in[16]; const float* vm_b = (const float*)d_in[17];
  const float* z_w  = (const float*)d_in[18]; const float* z_b  = (const float*)d_in[19];
  const float* m_w  = (const float*)d_in[20]; const float* m_b  = (const float*)d_in[21];

  float* out   = (float*)d_out;
  float* out_h = out;                        // doubles as h_next scratch
  float* out_c = out + 16777216;
  float* out_m = out + 33554432;

  char* ws = (char*)d_ws;
  // region A: cc (bf16, 134,217,728 B); aliased AFTER k_gate by attention scratch
  __hip_bfloat16* cc = (__hip_bfloat16*)ws;
  float* proj = (float*)(ws + 2097152);              //  5,242,880 B (alias cc, post-gate)
  float* Amat = (float*)(ws + 7340032);              //  8,388,608 B
  float* Zcat = (float*)(ws + 15728640);             //  2,097,152 B
  float* Cs   = (float*)(ws + 17825792);             //  3,145,728 B (ends 20,971,520)
  float* pool = (float*)(ws + 134217728);            // 2,097,152 B — aliases im region, post-conv

  // big path: im holds all 16 batches (67 MB); weights region relocated past it.
  bool big = (ws_size >= (size_t)202200000);
  size_t imOff = 134217728;
  size_t wOff  = big ? (imOff + 67108864) : 150994944;
  __hip_bfloat16* im  = (__hip_bfloat16*)(ws + imOff);
  __hip_bfloat16* wB  = (__hip_bfloat16*)(ws + wOff);                 //   589,824 B
  __hip_bfloat16* WhB = (__hip_bfloat16*)(ws + wOff +  589824);       //    24,576 B
  float* W2   = (float*)(ws + wOff +  614400);                        //    98,304 B
  float* bcv  = (float*)(ws + wOff +  712704);                        //       768 B
  float* gnsc = (float*)(ws + wOff +  713472);                        //    16,384 B
  float* gnsh = (float*)(ws + wOff +  729856);                        //    16,384 B

  hipLaunchKernelGGL(k_setup, dim3(1200), dim3(256), 0, stream, conv_w, m_w, wB, WhB);
  hipLaunchKernelGGL(k_w2, dim3(97), dim3(256), 0, stream, m_w, z_w, z_b, m_b, W2, bcv);
  if (big){
    hipLaunchKernelGGL(k_im,   dim3(2048),    dim3(256), 0, stream, x, h, im, 0);
    hipLaunchKernelGGL(k_conv, dim3(2048, 2), dim3(512), 0, stream, im, wB, cc, 0);
  } else {
    for (int q = 0; q < 4; q++){
      hipLaunchKernelGGL(k_im,   dim3(512),    dim3(256), 0, stream, x, h, im, q*4);
      hipLaunchKernelGGL(k_conv, dim3(512, 2), dim3(512), 0, stream, im, wB, cc, q*4);
    }
  }
  hipLaunchKernelGGL(k_gnstats, dim3(4096), dim3(256), 0, stream, cc, gn_w, gn_b, gnsc, gnsh);
  hipLaunchKernelGGL(k_gate, dim3(1024), dim3(256), 0, stream, cc, cst, gnsc, gnsh, out_c, out_h, pool);
  hipLaunchKernelGGL(k_poolm, dim3(1024), dim3(256), 0, stream, m, pool + 262144);
  hipLaunchKernelGGL(k_proj, dim3(80), dim3(256), 0, stream, pool,
                     qh_w,qh_b,kh_w,kh_b,vh_w,vh_b,km_w,km_b,vm_w,vm_b, proj);
  hipLaunchKernelGGL(k_scores, dim3(256,2,16), dim3(256), 0, stream, proj, Amat);
  hipLaunchKernelGGL(k_apply, dim3(2,16,4), dim3(256), 0, stream, proj, Amat, Zcat);
  hipLaunchKernelGGL(k_csmall, dim3(6,16), dim3(256), 0, stream, Zcat, W2, Cs);
  hipLaunchKernelGGL(k_final, dim3(4096), dim3(256), 0, stream, out_h, m, WhB, Cs, bcv, out_h, out_m);
}

// Round 17
// 584.359 us; speedup vs baseline: 1.2388x; 1.2388x over previous
//
#include <hip/hip_runtime.h>
#include <hip/hip_bf16.h>
#include <math.h>

typedef __attribute__((ext_vector_type(4))) float f4;
typedef __attribute__((ext_vector_type(4))) float f32x4;
typedef __attribute__((ext_vector_type(8))) short bf16x8;

#define HSZ 128
#define WSZ 128
#define HW 16384

__device__ __forceinline__ float sigm(float x){ return 1.f/(1.f+__expf(-x)); }
__device__ __forceinline__ float tanh_fast(float x){ return 1.f - 2.f/(1.f+__expf(2.f*x)); }
__device__ __forceinline__ float bf_lo(unsigned u){ return __uint_as_float(u<<16); }
__device__ __forceinline__ float bf_hi(unsigned u){ return __uint_as_float(u & 0xffff0000u); }

// ---------------- setup: conv weights -> bf16 [u=(dy*4+ck)*3+dx][256 oc][32 k]; WhB bf16 [192][64] ----
__global__ void k_setup(const float* __restrict__ conv_w, const float* __restrict__ m_w,
                        __hip_bfloat16* __restrict__ wB, __hip_bfloat16* __restrict__ WhB){
  int idx = blockIdx.x*256 + threadIdx.x;
  if (idx < 294912){
    int kk = idx & 31;
    int oc = (idx>>5) & 255;
    int q  = idx >> 13;              // (dy*4+ck)*3+dx
    int dx = q % 3; int t2 = q / 3; int ck = t2 & 3; int dy = t2 >> 2;
    int ic = ck*32 + kk;
    wB[idx] = __float2bfloat16(conv_w[((oc*128+ic)*3+dy)*3+dx]);
  } else if (idx < 294912 + 12288){
    int j = idx - 294912;
    int o = j >> 6, ci = j & 63;
    WhB[j] = __float2bfloat16(m_w[o*192 + 128 + ci]);
  }
}

// W2[o*128+zi] = sum_zo m_w[o*192+zo]*z_w[zo*128+zi];  bc[o] = m_w[o,:128]@z_b + m_b
__global__ void k_w2(const float* __restrict__ m_w, const float* __restrict__ z_w,
                     const float* __restrict__ z_b, const float* __restrict__ m_b,
                     float* __restrict__ W2, float* __restrict__ bc){
  int idx = blockIdx.x*256 + threadIdx.x;
  if (idx < 24576){
    int o = idx >> 7, zi = idx & 127;
    float s = 0.f;
    for (int zo=0; zo<128; zo++) s += m_w[o*192+zo]*z_w[zo*128+zi];
    W2[idx] = s;
  } else if (idx < 24576 + 192){
    int o = idx - 24576;
    float s = m_b[o];
    for (int zo=0; zo<128; zo++) s += m_w[o*192+zo]*z_b[zo];
    bc[o] = s;
  }
}

// ---------------- im pre-pass: [b][c][y][x] f32 (x,h) -> [bl][y][x][128ch] bf16 ----
__global__ __launch_bounds__(256) void k_im(const float* __restrict__ x,
    const float* __restrict__ h, __hip_bfloat16* __restrict__ im, int b0){
  __shared__ __hip_bfloat16 T[128*136];
  int bid = blockIdx.x; int y = bid & 127, bl = bid >> 7; int b = b0 + bl;
  int t = threadIdx.x;
  for (int idx=t; idx<4096; idx+=256){
    int c = idx>>5, xq = idx&31;
    const float* src = (c<64)? x : h; int cm = c&63;
    f4 v = *(const f4*)(src + ((((size_t)b*64+cm)*HSZ + y)*WSZ + xq*4));
    #pragma unroll
    for (int j=0;j<4;j++) T[(xq*4+j)*136 + c] = __float2bfloat16(v[j]);
  }
  __syncthreads();
  for (int idx=t; idx<2048; idx+=256){
    int xx = idx>>4, q = idx&15;
    uint4 v = *(const uint4*)&T[xx*136 + q*8];
    *(uint4*)(im + ((((size_t)bl*HSZ + y)*WSZ + xx)*128 + q*8)) = v;
  }
}

// ---------------- conv3x3 implicit-GEMM MFMA v12 ----------------
// R13 structure (1 row, 256 thr, input-only dbuf LDS pad-40, weights from global)
// + rolling register prefetch of the weight fragment for the NEXT (s,dx) step.
__global__ __launch_bounds__(256) void k_conv(const __hip_bfloat16* __restrict__ im,
    const __hip_bfloat16* __restrict__ wB, __hip_bfloat16* __restrict__ cc, int b0){
  __shared__ __align__(16) short LDS[17408];           // 34,816 B (epilogue OutL is max)
  short* buf0 = LDS;                                   // [132][40]
  short* buf1 = LDS + 5280;
  int bid = blockIdx.x;
  int y = bid & 127, bl = bid >> 7; int b = b0 + bl;
  int oc0 = blockIdx.y * 128;
  int t = threadIdx.x;
  int lane = t & 63, w = t >> 6;
  int ln15 = lane & 15, h8 = (lane>>4)*8;
  int ocw = (w>>1)*64, pxw = (w&1)*64;
  int px0 = t>>2, q0 = t&3;                            // static staging coords

  f32x4 acc[4][4];
  #pragma unroll
  for (int mi=0;mi<4;mi++)
    #pragma unroll
    for (int ni=0;ni<4;ni++) acc[mi][ni] = (f32x4){0.f,0.f,0.f,0.f};

  auto stage = [&](int s, short* dst){
    int dy = s>>2, ck = s&3;
    int yy = y + dy - 1;
    bool yok = (yy>=0) && (yy<HSZ);
    const __hip_bfloat16* rb = im + (((size_t)bl*HSZ + yy)*WSZ)*128 + ck*32;
    uint4 v0 = make_uint4(0u,0u,0u,0u);
    uint4 v1 = make_uint4(0u,0u,0u,0u);
    uint4 v2 = make_uint4(0u,0u,0u,0u);
    if (yok && px0>=1)       v0 = *(const uint4*)(rb + (size_t)(px0-1)*128 + q0*8);
    if (yok)                 v1 = *(const uint4*)(rb + (size_t)(px0+63)*128 + q0*8);
    if (yok && t<4)          v2 = *(const uint4*)(rb + (size_t)127*128 + q0*8);
    *(uint4*)&dst[px0*40 + q0*8]      = v0;
    *(uint4*)&dst[(px0+64)*40 + q0*8] = v1;
    if (t<16) *(uint4*)&dst[(128+(t>>2))*40 + q0*8] = v2;
  };
  auto ldw = [&](int u, bf16x8 af[4]){
    const __hip_bfloat16* wp = wB + (((size_t)u*256 + oc0 + ocw + ln15)*32 + h8);
    #pragma unroll
    for (int i=0;i<4;i++) af[i] = *(const bf16x8*)(wp + (size_t)i*16*32);
  };

  bf16x8 afc[4];
  stage(0, buf0);
  ldw(0, afc);
  __syncthreads();
  for (int s=0; s<12; s++){
    short* cur = (s&1)? buf1 : buf0;
    short* nxt = (s&1)? buf0 : buf1;
    if (s < 11) stage(s+1, nxt);
    #pragma unroll
    for (int dx=0; dx<3; dx++){
      int u = s*3 + dx;
      bf16x8 afn[4];
      bool more = (u < 35);
      if (more) ldw(u+1, afn);                 // in flight during this step's MFMAs
      bf16x8 bfr[4];
      #pragma unroll
      for (int i=0;i<4;i++) bfr[i] = *(const bf16x8*)&cur[(pxw + i*16 + ln15 + dx)*40 + h8];
      #pragma unroll
      for (int mi=0;mi<4;mi++)
        #pragma unroll
        for (int ni=0;ni<4;ni++)
          acc[mi][ni] = __builtin_amdgcn_mfma_f32_16x16x32_bf16(afc[mi], bfr[ni], acc[mi][ni], 0, 0, 0);
      if (more){
        #pragma unroll
        for (int i=0;i<4;i++) afc[i] = afn[i];
      }
    }
    __syncthreads();
  }

  // epilogue: transpose via LDS, write cc[b][oc][y][x] bf16
  __hip_bfloat16* OutL = (__hip_bfloat16*)LDS;         // [128][136]
  int hv4 = (lane>>4)*4;
  #pragma unroll
  for (int mi=0;mi<4;mi++)
    #pragma unroll
    for (int ni=0;ni<4;ni++){
      #pragma unroll
      for (int r=0;r<4;r++)
        OutL[(ocw + mi*16 + hv4 + r)*136 + pxw + ni*16 + ln15] = __float2bfloat16(acc[mi][ni][r]);
    }
  __syncthreads();
  for (int idx=t; idx<2048; idx+=256){
    int oc = idx>>4, qc = idx&15;
    uint4 v = *(const uint4*)&OutL[oc*136 + qc*8];
    *(uint4*)(cc + ((((size_t)b*256 + oc0 + oc)*HSZ + y)*WSZ + qc*8)) = v;
  }
}

// ---------------- instance-norm stats -> per-(b,ch) scale/shift ----------------
__global__ __launch_bounds__(256) void k_gnstats(const __hip_bfloat16* __restrict__ cc,
    const float* __restrict__ gn_w, const float* __restrict__ gn_b,
    float* __restrict__ scale, float* __restrict__ shift){
  int bc_ = blockIdx.x;                           // b*256+oc
  const uint4* p = (const uint4*)(cc + (size_t)bc_*HW);
  float s=0.f, ss=0.f;
  for (int ch=threadIdx.x; ch<2048; ch+=256){
    uint4 u = p[ch];
    unsigned uw[4] = {u.x, u.y, u.z, u.w};
    #pragma unroll
    for (int w=0; w<4; w++){
      float a = bf_lo(uw[w]);
      float b2 = bf_hi(uw[w]);
      s += a + b2; ss += a*a + b2*b2;
    }
  }
  for (int off=1; off<64; off<<=1){ s += __shfl_xor(s, off); ss += __shfl_xor(ss, off); }
  __shared__ float rs_[4], rss_[4];
  int wv = threadIdx.x>>6, ln = threadIdx.x&63;
  if (ln==0){ rs_[wv]=s; rss_[wv]=ss; }
  __syncthreads();
  if (threadIdx.x==0){
    float S = rs_[0]+rs_[1]+rs_[2]+rs_[3];
    float SS = rss_[0]+rss_[1]+rss_[2]+rss_[3];
    float mu = S*(1.f/16384.f);
    float var = SS*(1.f/16384.f) - mu*mu;
    float r = rsqrtf(var + 1e-5f);
    int oc = bc_ & 255;
    float sc = gn_w[oc]*r;
    scale[bc_] = sc;
    shift[bc_] = gn_b[oc] - mu*sc;
  }
}

// ---------------- LSTM gating: c_next + h_next + fused h-pool ----------------
__global__ __launch_bounds__(256) void k_gate(const __hip_bfloat16* __restrict__ cc,
    const float* __restrict__ cin, const float* __restrict__ scale, const float* __restrict__ shift,
    float* __restrict__ out_c, float* __restrict__ out_h, float* __restrict__ poolh){
  int bid = blockIdx.x;                 // b*64+c
  int b = bid>>6, c = bid&63;
  size_t base_i = ((size_t)b*256 + c)*HW;
  const uint4* pi = (const uint4*)(cc + base_i);
  const uint4* pf = (const uint4*)(cc + base_i + (size_t)64*HW);
  const uint4* pg = (const uint4*)(cc + base_i + (size_t)128*HW);
  const uint4* po = (const uint4*)(cc + base_i + (size_t)192*HW);
  float ssi = scale[b*256+c],     shi = shift[b*256+c];
  float ssf = scale[b*256+64+c],  shf = shift[b*256+64+c];
  float ssg = scale[b*256+128+c], shg = shift[b*256+128+c];
  float sso = scale[b*256+192+c], sho = shift[b*256+192+c];
  size_t pbase = ((size_t)b*64 + c)*HW;
  const f4* pc_ = (const f4*)(cin + pbase);
  f4* oc_ = (f4*)(out_c + pbase);
  f4* oh_ = (f4*)(out_h + pbase);
  int lane = threadIdx.x & 63;
  for (int ch = threadIdx.x; ch < 2048; ch += 256){
    uint4 ui = pi[ch], uf = pf[ch], ug = pg[ch], uo = po[ch];
    unsigned iu[4]={ui.x,ui.y,ui.z,ui.w}, fu[4]={uf.x,uf.y,uf.z,uf.w};
    unsigned gu[4]={ug.x,ug.y,ug.z,ug.w}, ou[4]={uo.x,uo.y,uo.z,uo.w};
    f4 ca = pc_[ch*2], cb = pc_[ch*2+1];
    float cvv[8] = {ca[0],ca[1],ca[2],ca[3],cb[0],cb[1],cb[2],cb[3]};
    float rc[8], rh[8];
    #pragma unroll
    for (int w=0; w<4; w++){
      #pragma unroll
      for (int hl=0; hl<2; hl++){
        int k = w*2+hl;
        float iv = (hl? bf_hi(iu[w]) : bf_lo(iu[w]))*ssi + shi;
        float fv = (hl? bf_hi(fu[w]) : bf_lo(fu[w]))*ssf + shf;
        float gv = (hl? bf_hi(gu[w]) : bf_lo(gu[w]))*ssg + shg;
        float ov = (hl? bf_hi(ou[w]) : bf_lo(ou[w]))*sso + sho;
        float cn = sigm(fv)*cvv[k] + sigm(iv)*tanh_fast(gv);
        rc[k] = cn;
        rh[k] = sigm(ov)*tanh_fast(cn);
      }
    }
    f4 o0 = {rc[0],rc[1],rc[2],rc[3]}, o1 = {rc[4],rc[5],rc[6],rc[7]};
    f4 h0 = {rh[0],rh[1],rh[2],rh[3]}, h1 = {rh[4],rh[5],rh[6],rh[7]};
    oc_[ch*2] = o0; oc_[ch*2+1] = o1;
    oh_[ch*2] = h0; oh_[ch*2+1] = h1;
    float ps = ((rh[0]+rh[1])+(rh[2]+rh[3])) + ((rh[4]+rh[5])+(rh[6]+rh[7]));
    ps += __shfl_xor(ps, 1);
    ps += __shfl_xor(ps, 2);
    ps += __shfl_xor(ps, 4);
    if ((lane & 7) == 0) poolh[(size_t)bid*256 + (ch>>3)] = ps*(1.f/64.f);
  }
}

// ---------------- pooling of m only: (B,64,HW) -> (B,64,256) ----------------
__global__ __launch_bounds__(256) void k_poolm(const float* __restrict__ m_in,
    float* __restrict__ poolm){
  int pc = blockIdx.x;                  // b*64+c
  const float* src = m_in + (size_t)pc*HW;
  float* dst = poolm + (size_t)pc*256;
  int n = threadIdx.x;                  // token
  const f4* p = (const f4*)(src + n*64);
  float s = 0.f;
  #pragma unroll
  for (int i=0;i<16;i++){ f4 v = p[i]; s += (v[0]+v[1]) + (v[2]+v[3]); }
  dst[n] = s*(1.f/64.f);
}

// ---------------- 5 pooled projections ----------------
__global__ __launch_bounds__(256) void k_proj(const float* __restrict__ pool,
    const float* qw,const float* qb,const float* kw,const float* kb,
    const float* vw,const float* vb,const float* kmw,const float* kmb,
    const float* vmw,const float* vmb, float* __restrict__ proj){
  int bid = blockIdx.x;  // b*5+p
  int p = bid % 5, b = bid / 5;
  const float* P = pool + (p>=3? 262144:0) + (size_t)b*16384;
  const float* W; const float* Bs;
  if (p==0){W=qw;Bs=qb;} else if(p==1){W=kw;Bs=kb;} else if(p==2){W=vw;Bs=vb;}
  else if (p==3){W=kmw;Bs=kmb;} else {W=vmw;Bs=vmb;}
  int n = threadIdx.x;
  float acc[64];
  #pragma unroll
  for (int o=0;o<64;o++) acc[o]=0.f;
  for (int c=0;c<64;c++){
    float pv = P[c*256+n];
    #pragma unroll
    for (int o=0;o<64;o++) acc[o] += W[o*64+c]*pv;
  }
  float* dst = proj + (size_t)p*262144 + (size_t)b*16384;
  #pragma unroll
  for (int o=0;o<64;o++) dst[o*256+n] = acc[o] + Bs[o];
}

// ---------------- attention scores + softmax ----------------
__global__ __launch_bounds__(256) void k_scores(const float* __restrict__ proj, float* __restrict__ A){
  int n = blockIdx.x, ty = blockIdx.y, b = blockIdx.z;
  const float* Q = proj + (size_t)b*16384;
  const float* K = proj + (size_t)(ty==0?1:3)*262144 + (size_t)b*16384;
  int mm = threadIdx.x;
  float s = 0.f;
  for (int c=0;c<64;c++) s += Q[c*256+n]*K[c*256+mm];
  float mx = s;
  for (int off=1; off<64; off<<=1) mx = fmaxf(mx, __shfl_xor(mx, off));
  __shared__ float r1[4], r2[4];
  int wv = threadIdx.x>>6, ln = threadIdx.x&63;
  if (ln==0) r1[wv]=mx;
  __syncthreads();
  mx = fmaxf(fmaxf(r1[0],r1[1]),fmaxf(r1[2],r1[3]));
  float e = __expf(s-mx);
  float sm = e;
  for (int off=1; off<64; off<<=1) sm += __shfl_xor(sm, off);
  if (ln==0) r2[wv]=sm;
  __syncthreads();
  sm = r2[0]+r2[1]+r2[2]+r2[3];
  A[(((size_t)ty*16+b)*256+n)*256+mm] = e/sm;
}

// ---------------- Z = V @ A^T (c-split for occupancy) ----------------
__global__ __launch_bounds__(256) void k_apply(const float* __restrict__ proj,
    const float* __restrict__ A, float* __restrict__ Zcat){
  int ty = blockIdx.x, b = blockIdx.y, cq = blockIdx.z;
  const float* V = proj + (size_t)(ty==0?2:4)*262144 + (size_t)b*16384 + (size_t)cq*16*256;
  const float* Ar = A + (((size_t)ty*16+b)*256 + threadIdx.x)*256;
  float acc[16];
  #pragma unroll
  for (int c=0;c<16;c++) acc[c]=0.f;
  for (int mm=0; mm<256; mm++){
    float a = Ar[mm];
    #pragma unroll
    for (int c=0;c<16;c++) acc[c] += V[c*256+mm]*a;
  }
  float* dst = Zcat + ((size_t)b*128 + ty*64 + cq*16)*256 + threadIdx.x;
  #pragma unroll
  for (int c=0;c<16;c++) dst[c*256] = acc[c];
}

// ---------------- Csmall = W2 @ [Zh;Zm] (192 x 256 per b), 32-out split ----------------
__global__ __launch_bounds__(256) void k_csmall(const float* __restrict__ Zcat,
    const float* __restrict__ W2, float* __restrict__ Cs){
  int oq = blockIdx.x, b = blockIdx.y;
  int o0 = oq*32;
  int n = threadIdx.x;
  float acc[32];
  #pragma unroll
  for (int o=0;o<32;o++) acc[o]=0.f;
  for (int zi=0; zi<128; zi++){
    float z = Zcat[((size_t)b*128+zi)*256 + n];
    #pragma unroll
    for (int o=0;o<32;o++) acc[o] += W2[(o0+o)*128 + zi]*z;
  }
  float* dst = Cs + ((size_t)b*192 + o0)*256 + n;
  #pragma unroll
  for (int o=0;o<32;o++) dst[o*256] = acc[o];
}

// ---------------- final: MFMA matvec + LDS-staged bilinear taps + gates ----------------
__global__ __launch_bounds__(256, 3) void k_final(
    const float* __restrict__ hn, const float* __restrict__ m_in,
    const __hip_bfloat16* __restrict__ WhB, const float* __restrict__ Cs,
    const float* __restrict__ bcv, float* __restrict__ out_h, float* __restrict__ out_m){
  __shared__ float rowF[64*69];          // [64 ch][64 px + pad5]
  __shared__ float CsL[192*36];          // [192 c'][2 rows x 16 + pad4]
  int bid = blockIdx.x;
  int xh = bid & 1, y = (bid>>1) & 127, b = bid >> 8;
  int x0 = xh*64;
  int t = threadIdx.x, lane = t & 63, w = t >> 6;
  int ln15 = lane & 15, hi = lane >> 4, h8 = hi*8;

  float sy = (y+0.5f)*0.125f - 0.5f;
  int iy = (int)floorf(sy); float fy = sy - (float)iy;
  int ya = min(max(iy,0),15), yb = min(max(iy+1,0),15);

  for (int idx=t; idx<1024; idx+=256){
    int c = idx>>4, xq = idx&15;
    f4 v = *(const f4*)(hn + ((((size_t)b*64+c)*HSZ + y)*WSZ + x0 + xq*4));
    float* d = &rowF[c*69 + xq*4];
    d[0]=v[0]; d[1]=v[1]; d[2]=v[2]; d[3]=v[3];
  }
  for (int idx=t; idx<1536; idx+=256){
    int cp = idx>>3, rr = (idx>>2)&1, q = idx&3;
    int ry = rr? yb : ya;
    f4 v = *(const f4*)(Cs + (((size_t)b*192 + cp)*256 + ry*16 + q*4));
    *(f4*)&CsL[cp*36 + rr*16 + q*4] = v;
  }
  __syncthreads();

  bf16x8 bfr[2];
  #pragma unroll
  for (int ks=0; ks<2; ks++){
    union { bf16x8 v; __hip_bfloat16 e[8]; } u;
    #pragma unroll
    for (int j=0;j<8;j++)
      u.e[j] = __float2bfloat16(rowF[(ks*32 + h8 + j)*69 + w*16 + ln15]);
    bfr[ks] = u.v;
  }
  f32x4 acc[12];
  #pragma unroll
  for (int mt=0;mt<12;mt++) acc[mt] = (f32x4){0.f,0.f,0.f,0.f};
  #pragma unroll
  for (int ks=0; ks<2; ks++){
    #pragma unroll
    for (int mt=0; mt<12; mt++){
      bf16x8 af = *(const bf16x8*)(WhB + ((mt*16+ln15)*64 + ks*32 + h8));
      acc[mt] = __builtin_amdgcn_mfma_f32_16x16x32_bf16(af, bfr[ks], acc[mt], 0, 0, 0);
    }
  }

  int xg = x0 + w*16 + ln15;
  float sx = (xg+0.5f)*0.125f - 0.5f;
  int ix = (int)floorf(sx); float fx = sx - (float)ix;
  int xa = min(max(ix,0),15), xb2 = min(max(ix+1,0),15);
  float w00=(1.f-fy)*(1.f-fx), w01=(1.f-fy)*fx, w10=fy*(1.f-fx), w11=fy*fx;
  int o00 = xa, o01 = xb2, o10 = 16+xa, o11 = 16+xb2;
  #pragma unroll
  for (int mt=0; mt<4; mt++){
    #pragma unroll
    for (int r=0; r<4; r++){
      int c = mt*16 + hi*4 + r;
      const float* p0 = &CsL[c*36];
      const float* p1 = &CsL[(64+c)*36];
      const float* p2 = &CsL[(128+c)*36];
      float vo = acc[mt][r]   + p0[o00]*w00 + p0[o01]*w01 + p0[o10]*w10 + p0[o11]*w11 + bcv[c];
      float vg = acc[mt+4][r] + p1[o00]*w00 + p1[o01]*w01 + p1[o10]*w10 + p1[o11]*w11 + bcv[64+c];
      float vi = acc[mt+8][r] + p2[o00]*w00 + p2[o01]*w01 + p2[o10]*w10 + p2[o11]*w11 + bcv[128+c];
      size_t pix = (((size_t)b*64+c)*HSZ + y)*WSZ + xg;
      float mv = m_in[pix];
      float smi = sigm(vi);
      float nm = (1.f-smi)*mv + smi*tanh_fast(vg);
      float nh = sigm(vo)*nm;
      out_h[pix] = nh;
      out_m[pix] = nm;
    }
  }
}

extern "C" void kernel_launch(void* const* d_in, const int* in_sizes, int n_in,
                              void* d_out, int out_size, void* d_ws, size_t ws_size,
                              hipStream_t stream){
  (void)in_sizes; (void)n_in; (void)out_size;
  const float* x    = (const float*)d_in[0];
  const float* cst  = (const float*)d_in[1];
  const float* h    = (const float*)d_in[2];
  const float* m    = (const float*)d_in[3];
  const float* conv_w = (const float*)d_in[4];
  // d_in[5] conv_b: exactly cancelled by instance norm — unused
  const float* gn_w = (const float*)d_in[6];
  const float* gn_b = (const float*)d_in[7];
  const float* qh_w = (const float*)d_in[8];  const float* qh_b = (const float*)d_in[9];
  const float* kh_w = (const float*)d_in[10]; const float* kh_b = (const float*)d_in[11];
  const float* vh_w = (const float*)d_in[12]; const float* vh_b = (const float*)d_in[13];
  const float* km_w = (const float*)d_in[14]; const float* km_b = (const float*)d_in[15];
  const float* vm_w = (const float*)d_in[16]; const float* vm_b = (const float*)d_in[17];
  const float* z_w  = (const float*)d_in[18]; const float* z_b  = (const float*)d_in[19];
  const float* m_w  = (const float*)d_in[20]; const float* m_b  = (const float*)d_in[21];

  float* out   = (float*)d_out;
  float* out_h = out;                        // doubles as h_next scratch
  float* out_c = out + 16777216;
  float* out_m = out + 33554432;

  char* ws = (char*)d_ws;
  // region A: cc (bf16, 134,217,728 B); aliased AFTER k_gate by attention scratch
  __hip_bfloat16* cc = (__hip_bfloat16*)ws;
  float* proj = (float*)(ws + 2097152);              //  5,242,880 B (alias cc, post-gate)
  float* Amat = (float*)(ws + 7340032);              //  8,388,608 B
  float* Zcat = (float*)(ws + 15728640);             //  2,097,152 B
  float* Cs   = (float*)(ws + 17825792);             //  3,145,728 B (ends 20,971,520)
  float* pool = (float*)(ws + 134217728);            // 2,097,152 B — aliases im region, post-conv

  // big path: im holds all 16 batches (67 MB); weights region relocated past it.
  bool big = (ws_size >= (size_t)202200000);
  size_t imOff = 134217728;
  size_t wOff  = big ? (imOff + 67108864) : 150994944;
  __hip_bfloat16* im  = (__hip_bfloat16*)(ws + imOff);
  __hip_bfloat16* wB  = (__hip_bfloat16*)(ws + wOff);                 //   589,824 B
  __hip_bfloat16* WhB = (__hip_bfloat16*)(ws + wOff +  589824);       //    24,576 B
  float* W2   = (float*)(ws + wOff +  614400);                        //    98,304 B
  float* bcv  = (float*)(ws + wOff +  712704);                        //       768 B
  float* gnsc = (float*)(ws + wOff +  713472);                        //    16,384 B
  float* gnsh = (float*)(ws + wOff +  729856);                        //    16,384 B

  hipLaunchKernelGGL(k_setup, dim3(1200), dim3(256), 0, stream, conv_w, m_w, wB, WhB);
  hipLaunchKernelGGL(k_w2, dim3(97), dim3(256), 0, stream, m_w, z_w, z_b, m_b, W2, bcv);
  if (big){
    hipLaunchKernelGGL(k_im,   dim3(2048),    dim3(256), 0, stream, x, h, im, 0);
    hipLaunchKernelGGL(k_conv, dim3(2048, 2), dim3(256), 0, stream, im, wB, cc, 0);
  } else {
    for (int q = 0; q < 4; q++){
      hipLaunchKernelGGL(k_im,   dim3(512),    dim3(256), 0, stream, x, h, im, q*4);
      hipLaunchKernelGGL(k_conv, dim3(512, 2), dim3(256), 0, stream, im, wB, cc, q*4);
    }
  }
  hipLaunchKernelGGL(k_gnstats, dim3(4096), dim3(256), 0, stream, cc, gn_w, gn_b, gnsc, gnsh);
  hipLaunchKernelGGL(k_gate, dim3(1024), dim3(256), 0, stream, cc, cst, gnsc, gnsh, out_c, out_h, pool);
  hipLaunchKernelGGL(k_poolm, dim3(1024), dim3(256), 0, stream, m, pool + 262144);
  hipLaunchKernelGGL(k_proj, dim3(80), dim3(256), 0, stream, pool,
                     qh_w,qh_b,kh_w,kh_b,vh_w,vh_b,km_w,km_b,vm_w,vm_b, proj);
  hipLaunchKernelGGL(k_scores, dim3(256,2,16), dim3(256), 0, stream, proj, Amat);
  hipLaunchKernelGGL(k_apply, dim3(2,16,4), dim3(256), 0, stream, proj, Amat, Zcat);
  hipLaunchKernelGGL(k_csmall, dim3(6,16), dim3(256), 0, stream, Zcat, W2, Cs);
  hipLaunchKernelGGL(k_final, dim3(4096), dim3(256), 0, stream, out_h, m, WhB, Cs, bcv, out_h, out_m);
}

// Round 18
// 577.560 us; speedup vs baseline: 1.2534x; 1.0118x over previous
//
#include <hip/hip_runtime.h>
#include <hip/hip_bf16.h>
#include <math.h>

typedef __attribute__((ext_vector_type(4))) float f4;
typedef __attribute__((ext_vector_type(4))) float f32x4;
typedef __attribute__((ext_vector_type(8))) short bf16x8;

#define HSZ 128
#define WSZ 128
#define HW 16384

__device__ __forceinline__ float sigm(float x){ return 1.f/(1.f+__expf(-x)); }
__device__ __forceinline__ float tanh_fast(float x){ return 1.f - 2.f/(1.f+__expf(2.f*x)); }
__device__ __forceinline__ float bf_lo(unsigned u){ return __uint_as_float(u<<16); }
__device__ __forceinline__ float bf_hi(unsigned u){ return __uint_as_float(u & 0xffff0000u); }

// ---------------- setup (merged): conv weights bf16, WhB bf16, W2, bc ----------------
__global__ void k_setup(const float* __restrict__ conv_w, const float* __restrict__ m_w,
                        const float* __restrict__ z_w, const float* __restrict__ z_b,
                        const float* __restrict__ m_b,
                        __hip_bfloat16* __restrict__ wB, __hip_bfloat16* __restrict__ WhB,
                        float* __restrict__ W2, float* __restrict__ bc){
  int idx = blockIdx.x*256 + threadIdx.x;
  if (idx < 294912){
    int kk = idx & 31;
    int oc = (idx>>5) & 255;
    int q  = idx >> 13;              // (dy*4+ck)*3+dx
    int dx = q % 3; int t2 = q / 3; int ck = t2 & 3; int dy = t2 >> 2;
    int ic = ck*32 + kk;
    wB[idx] = __float2bfloat16(conv_w[((oc*128+ic)*3+dy)*3+dx]);
  } else if (idx < 307200){
    int j = idx - 294912;
    int o = j >> 6, ci = j & 63;
    WhB[j] = __float2bfloat16(m_w[o*192 + 128 + ci]);
  } else if (idx < 331776){
    int j = idx - 307200;
    int o = j >> 7, zi = j & 127;
    float s = 0.f;
    for (int zo=0; zo<128; zo++) s += m_w[o*192+zo]*z_w[zo*128+zi];
    W2[j] = s;
  } else if (idx < 331968){
    int o = idx - 331776;
    float s = m_b[o];
    for (int zo=0; zo<128; zo++) s += m_w[o*192+zo]*z_b[zo];
    bc[o] = s;
  }
}

// ---------------- im pre-pass: [b][c][y][x] f32 (x,h) -> [bl][y][x][128ch] bf16 ----
__global__ __launch_bounds__(256) void k_im(const float* __restrict__ x,
    const float* __restrict__ h, __hip_bfloat16* __restrict__ im, int b0){
  __shared__ __hip_bfloat16 T[128*136];
  int bid = blockIdx.x; int y = bid & 127, bl = bid >> 7; int b = b0 + bl;
  int t = threadIdx.x;
  for (int idx=t; idx<4096; idx+=256){
    int c = idx>>5, xq = idx&31;
    const float* src = (c<64)? x : h; int cm = c&63;
    f4 v = *(const f4*)(src + ((((size_t)b*64+cm)*HSZ + y)*WSZ + xq*4));
    #pragma unroll
    for (int j=0;j<4;j++) T[(xq*4+j)*136 + c] = __float2bfloat16(v[j]);
  }
  __syncthreads();
  for (int idx=t; idx<2048; idx+=256){
    int xx = idx>>4, q = idx&15;
    uint4 v = *(const uint4*)&T[xx*136 + q*8];
    *(uint4*)(im + ((((size_t)bl*HSZ + y)*WSZ + xx)*128 + q*8)) = v;
  }
}

// ---------------- conv3x3 implicit-GEMM MFMA v13 ----------------
// v12 (1-row, 256 thr, dbuf input LDS pad-40, weights from global + rolling
// register prefetch) + XCD-swizzled blockIdx.x: each XCD owns contiguous y
// ranges so dy-halo row re-reads hit same-XCD L2 instead of HBM.
__global__ __launch_bounds__(256) void k_conv(const __hip_bfloat16* __restrict__ im,
    const __hip_bfloat16* __restrict__ wB, __hip_bfloat16* __restrict__ cc, int b0){
  __shared__ __align__(16) short LDS[17408];           // 34,816 B (epilogue OutL is max)
  short* buf0 = LDS;                                   // [132][40]
  short* buf1 = LDS + 5280;
  int bid0 = blockIdx.x;
  int cpx = gridDim.x >> 3;                            // gridDim.x % 8 == 0 (512 or 2048)
  int bid = (bid0 & 7)*cpx + (bid0 >> 3);              // bijective XCD swizzle
  int y = bid & 127, bl = bid >> 7; int b = b0 + bl;
  int oc0 = blockIdx.y * 128;
  int t = threadIdx.x;
  int lane = t & 63, w = t >> 6;
  int ln15 = lane & 15, h8 = (lane>>4)*8;
  int ocw = (w>>1)*64, pxw = (w&1)*64;
  int px0 = t>>2, q0 = t&3;                            // static staging coords

  f32x4 acc[4][4];
  #pragma unroll
  for (int mi=0;mi<4;mi++)
    #pragma unroll
    for (int ni=0;ni<4;ni++) acc[mi][ni] = (f32x4){0.f,0.f,0.f,0.f};

  auto stage = [&](int s, short* dst){
    int dy = s>>2, ck = s&3;
    int yy = y + dy - 1;
    bool yok = (yy>=0) && (yy<HSZ);
    const __hip_bfloat16* rb = im + (((size_t)bl*HSZ + yy)*WSZ)*128 + ck*32;
    uint4 v0 = make_uint4(0u,0u,0u,0u);
    uint4 v1 = make_uint4(0u,0u,0u,0u);
    uint4 v2 = make_uint4(0u,0u,0u,0u);
    if (yok && px0>=1)       v0 = *(const uint4*)(rb + (size_t)(px0-1)*128 + q0*8);
    if (yok)                 v1 = *(const uint4*)(rb + (size_t)(px0+63)*128 + q0*8);
    if (yok && t<4)          v2 = *(const uint4*)(rb + (size_t)127*128 + q0*8);
    *(uint4*)&dst[px0*40 + q0*8]      = v0;
    *(uint4*)&dst[(px0+64)*40 + q0*8] = v1;
    if (t<16) *(uint4*)&dst[(128+(t>>2))*40 + q0*8] = v2;
  };
  auto ldw = [&](int u, bf16x8 af[4]){
    const __hip_bfloat16* wp = wB + (((size_t)u*256 + oc0 + ocw + ln15)*32 + h8);
    #pragma unroll
    for (int i=0;i<4;i++) af[i] = *(const bf16x8*)(wp + (size_t)i*16*32);
  };

  bf16x8 afc[4];
  stage(0, buf0);
  ldw(0, afc);
  __syncthreads();
  for (int s=0; s<12; s++){
    short* cur = (s&1)? buf1 : buf0;
    short* nxt = (s&1)? buf0 : buf1;
    if (s < 11) stage(s+1, nxt);
    #pragma unroll
    for (int dx=0; dx<3; dx++){
      int u = s*3 + dx;
      bf16x8 afn[4];
      bool more = (u < 35);
      if (more) ldw(u+1, afn);                 // in flight during this step's MFMAs
      bf16x8 bfr[4];
      #pragma unroll
      for (int i=0;i<4;i++) bfr[i] = *(const bf16x8*)&cur[(pxw + i*16 + ln15 + dx)*40 + h8];
      #pragma unroll
      for (int mi=0;mi<4;mi++)
        #pragma unroll
        for (int ni=0;ni<4;ni++)
          acc[mi][ni] = __builtin_amdgcn_mfma_f32_16x16x32_bf16(afc[mi], bfr[ni], acc[mi][ni], 0, 0, 0);
      if (more){
        #pragma unroll
        for (int i=0;i<4;i++) afc[i] = afn[i];
      }
    }
    __syncthreads();
  }

  // epilogue: transpose via LDS, write cc[b][oc][y][x] bf16
  __hip_bfloat16* OutL = (__hip_bfloat16*)LDS;         // [128][136]
  int hv4 = (lane>>4)*4;
  #pragma unroll
  for (int mi=0;mi<4;mi++)
    #pragma unroll
    for (int ni=0;ni<4;ni++){
      #pragma unroll
      for (int r=0;r<4;r++)
        OutL[(ocw + mi*16 + hv4 + r)*136 + pxw + ni*16 + ln15] = __float2bfloat16(acc[mi][ni][r]);
    }
  __syncthreads();
  for (int idx=t; idx<2048; idx+=256){
    int oc = idx>>4, qc = idx&15;
    uint4 v = *(const uint4*)&OutL[oc*136 + qc*8];
    *(uint4*)(cc + ((((size_t)b*256 + oc0 + oc)*HSZ + y)*WSZ + qc*8)) = v;
  }
}

// ---------------- instance-norm stats -> per-(b,ch) scale/shift ----------------
__global__ __launch_bounds__(256) void k_gnstats(const __hip_bfloat16* __restrict__ cc,
    const float* __restrict__ gn_w, const float* __restrict__ gn_b,
    float* __restrict__ scale, float* __restrict__ shift){
  int bc_ = blockIdx.x;                           // b*256+oc
  const uint4* p = (const uint4*)(cc + (size_t)bc_*HW);
  float s=0.f, ss=0.f;
  for (int ch=threadIdx.x; ch<2048; ch+=256){
    uint4 u = p[ch];
    unsigned uw[4] = {u.x, u.y, u.z, u.w};
    #pragma unroll
    for (int w=0; w<4; w++){
      float a = bf_lo(uw[w]);
      float b2 = bf_hi(uw[w]);
      s += a + b2; ss += a*a + b2*b2;
    }
  }
  for (int off=1; off<64; off<<=1){ s += __shfl_xor(s, off); ss += __shfl_xor(ss, off); }
  __shared__ float rs_[4], rss_[4];
  int wv = threadIdx.x>>6, ln = threadIdx.x&63;
  if (ln==0){ rs_[wv]=s; rss_[wv]=ss; }
  __syncthreads();
  if (threadIdx.x==0){
    float S = rs_[0]+rs_[1]+rs_[2]+rs_[3];
    float SS = rss_[0]+rss_[1]+rss_[2]+rss_[3];
    float mu = S*(1.f/16384.f);
    float var = SS*(1.f/16384.f) - mu*mu;
    float r = rsqrtf(var + 1e-5f);
    int oc = bc_ & 255;
    float sc = gn_w[oc]*r;
    scale[bc_] = sc;
    shift[bc_] = gn_b[oc] - mu*sc;
  }
}

// ---------------- LSTM gating: c_next + h_next + fused h-pool ----------------
__global__ __launch_bounds__(256) void k_gate(const __hip_bfloat16* __restrict__ cc,
    const float* __restrict__ cin, const float* __restrict__ scale, const float* __restrict__ shift,
    float* __restrict__ out_c, float* __restrict__ out_h, float* __restrict__ poolh){
  int bid = blockIdx.x;                 // b*64+c
  int b = bid>>6, c = bid&63;
  size_t base_i = ((size_t)b*256 + c)*HW;
  const uint4* pi = (const uint4*)(cc + base_i);
  const uint4* pf = (const uint4*)(cc + base_i + (size_t)64*HW);
  const uint4* pg = (const uint4*)(cc + base_i + (size_t)128*HW);
  const uint4* po = (const uint4*)(cc + base_i + (size_t)192*HW);
  float ssi = scale[b*256+c],     shi = shift[b*256+c];
  float ssf = scale[b*256+64+c],  shf = shift[b*256+64+c];
  float ssg = scale[b*256+128+c], shg = shift[b*256+128+c];
  float sso = scale[b*256+192+c], sho = shift[b*256+192+c];
  size_t pbase = ((size_t)b*64 + c)*HW;
  const f4* pc_ = (const f4*)(cin + pbase);
  f4* oc_ = (f4*)(out_c + pbase);
  f4* oh_ = (f4*)(out_h + pbase);
  int lane = threadIdx.x & 63;
  for (int ch = threadIdx.x; ch < 2048; ch += 256){
    uint4 ui = pi[ch], uf = pf[ch], ug = pg[ch], uo = po[ch];
    unsigned iu[4]={ui.x,ui.y,ui.z,ui.w}, fu[4]={uf.x,uf.y,uf.z,uf.w};
    unsigned gu[4]={ug.x,ug.y,ug.z,ug.w}, ou[4]={uo.x,uo.y,uo.z,uo.w};
    f4 ca = pc_[ch*2], cb = pc_[ch*2+1];
    float cvv[8] = {ca[0],ca[1],ca[2],ca[3],cb[0],cb[1],cb[2],cb[3]};
    float rc[8], rh[8];
    #pragma unroll
    for (int w=0; w<4; w++){
      #pragma unroll
      for (int hl=0; hl<2; hl++){
        int k = w*2+hl;
        float iv = (hl? bf_hi(iu[w]) : bf_lo(iu[w]))*ssi + shi;
        float fv = (hl? bf_hi(fu[w]) : bf_lo(fu[w]))*ssf + shf;
        float gv = (hl? bf_hi(gu[w]) : bf_lo(gu[w]))*ssg + shg;
        float ov = (hl? bf_hi(ou[w]) : bf_lo(ou[w]))*sso + sho;
        float cn = sigm(fv)*cvv[k] + sigm(iv)*tanh_fast(gv);
        rc[k] = cn;
        rh[k] = sigm(ov)*tanh_fast(cn);
      }
    }
    f4 o0 = {rc[0],rc[1],rc[2],rc[3]}, o1 = {rc[4],rc[5],rc[6],rc[7]};
    f4 h0 = {rh[0],rh[1],rh[2],rh[3]}, h1 = {rh[4],rh[5],rh[6],rh[7]};
    oc_[ch*2] = o0; oc_[ch*2+1] = o1;
    oh_[ch*2] = h0; oh_[ch*2+1] = h1;
    float ps = ((rh[0]+rh[1])+(rh[2]+rh[3])) + ((rh[4]+rh[5])+(rh[6]+rh[7]));
    ps += __shfl_xor(ps, 1);
    ps += __shfl_xor(ps, 2);
    ps += __shfl_xor(ps, 4);
    if ((lane & 7) == 0) poolh[(size_t)bid*256 + (ch>>3)] = ps*(1.f/64.f);
  }
}

// ---------------- pooling of m only: (B,64,HW) -> (B,64,256) ----------------
__global__ __launch_bounds__(256) void k_poolm(const float* __restrict__ m_in,
    float* __restrict__ poolm){
  int pc = blockIdx.x;                  // b*64+c
  const float* src = m_in + (size_t)pc*HW;
  float* dst = poolm + (size_t)pc*256;
  int n = threadIdx.x;                  // token
  const f4* p = (const f4*)(src + n*64);
  float s = 0.f;
  #pragma unroll
  for (int i=0;i<16;i++){ f4 v = p[i]; s += (v[0]+v[1]) + (v[2]+v[3]); }
  dst[n] = s*(1.f/64.f);
}

// ---------------- 5 pooled projections ----------------
__global__ __launch_bounds__(256) void k_proj(const float* __restrict__ pool,
    const float* qw,const float* qb,const float* kw,const float* kb,
    const float* vw,const float* vb,const float* kmw,const float* kmb,
    const float* vmw,const float* vmb, float* __restrict__ proj){
  int bid = blockIdx.x;  // b*5+p
  int p = bid % 5, b = bid / 5;
  const float* P = pool + (p>=3? 262144:0) + (size_t)b*16384;
  const float* W; const float* Bs;
  if (p==0){W=qw;Bs=qb;} else if(p==1){W=kw;Bs=kb;} else if(p==2){W=vw;Bs=vb;}
  else if (p==3){W=kmw;Bs=kmb;} else {W=vmw;Bs=vmb;}
  int n = threadIdx.x;
  float acc[64];
  #pragma unroll
  for (int o=0;o<64;o++) acc[o]=0.f;
  for (int c=0;c<64;c++){
    float pv = P[c*256+n];
    #pragma unroll
    for (int o=0;o<64;o++) acc[o] += W[o*64+c]*pv;
  }
  float* dst = proj + (size_t)p*262144 + (size_t)b*16384;
  #pragma unroll
  for (int o=0;o<64;o++) dst[o*256+n] = acc[o] + Bs[o];
}

// ---------------- attention scores + softmax ----------------
__global__ __launch_bounds__(256) void k_scores(const float* __restrict__ proj, float* __restrict__ A){
  int n = blockIdx.x, ty = blockIdx.y, b = blockIdx.z;
  const float* Q = proj + (size_t)b*16384;
  const float* K = proj + (size_t)(ty==0?1:3)*262144 + (size_t)b*16384;
  int mm = threadIdx.x;
  float s = 0.f;
  for (int c=0;c<64;c++) s += Q[c*256+n]*K[c*256+mm];
  float mx = s;
  for (int off=1; off<64; off<<=1) mx = fmaxf(mx, __shfl_xor(mx, off));
  __shared__ float r1[4], r2[4];
  int wv = threadIdx.x>>6, ln = threadIdx.x&63;
  if (ln==0) r1[wv]=mx;
  __syncthreads();
  mx = fmaxf(fmaxf(r1[0],r1[1]),fmaxf(r1[2],r1[3]));
  float e = __expf(s-mx);
  float sm = e;
  for (int off=1; off<64; off<<=1) sm += __shfl_xor(sm, off);
  if (ln==0) r2[wv]=sm;
  __syncthreads();
  sm = r2[0]+r2[1]+r2[2]+r2[3];
  A[(((size_t)ty*16+b)*256+n)*256+mm] = e/sm;
}

// ---------------- Z = V @ A^T (c-split for occupancy) ----------------
__global__ __launch_bounds__(256) void k_apply(const float* __restrict__ proj,
    const float* __restrict__ A, float* __restrict__ Zcat){
  int ty = blockIdx.x, b = blockIdx.y, cq = blockIdx.z;
  const float* V = proj + (size_t)(ty==0?2:4)*262144 + (size_t)b*16384 + (size_t)cq*16*256;
  const float* Ar = A + (((size_t)ty*16+b)*256 + threadIdx.x)*256;
  float acc[16];
  #pragma unroll
  for (int c=0;c<16;c++) acc[c]=0.f;
  for (int mm=0; mm<256; mm++){
    float a = Ar[mm];
    #pragma unroll
    for (int c=0;c<16;c++) acc[c] += V[c*256+mm]*a;
  }
  float* dst = Zcat + ((size_t)b*128 + ty*64 + cq*16)*256 + threadIdx.x;
  #pragma unroll
  for (int c=0;c<16;c++) dst[c*256] = acc[c];
}

// ---------------- Csmall = W2 @ [Zh;Zm] (192 x 256 per b), 32-out split ----------------
__global__ __launch_bounds__(256) void k_csmall(const float* __restrict__ Zcat,
    const float* __restrict__ W2, float* __restrict__ Cs){
  int oq = blockIdx.x, b = blockIdx.y;
  int o0 = oq*32;
  int n = threadIdx.x;
  float acc[32];
  #pragma unroll
  for (int o=0;o<32;o++) acc[o]=0.f;
  for (int zi=0; zi<128; zi++){
    float z = Zcat[((size_t)b*128+zi)*256 + n];
    #pragma unroll
    for (int o=0;o<32;o++) acc[o] += W2[(o0+o)*128 + zi]*z;
  }
  float* dst = Cs + ((size_t)b*192 + o0)*256 + n;
  #pragma unroll
  for (int o=0;o<32;o++) dst[o*256] = acc[o];
}

// ---------------- final: MFMA matvec + LDS-staged bilinear taps + gates ----------------
__global__ __launch_bounds__(256, 3) void k_final(
    const float* __restrict__ hn, const float* __restrict__ m_in,
    const __hip_bfloat16* __restrict__ WhB, const float* __restrict__ Cs,
    const float* __restrict__ bcv, float* __restrict__ out_h, float* __restrict__ out_m){
  __shared__ float rowF[64*69];          // [64 ch][64 px + pad5]
  __shared__ float CsL[192*36];          // [192 c'][2 rows x 16 + pad4]
  int bid = blockIdx.x;
  int xh = bid & 1, y = (bid>>1) & 127, b = bid >> 8;
  int x0 = xh*64;
  int t = threadIdx.x, lane = t & 63, w = t >> 6;
  int ln15 = lane & 15, hi = lane >> 4, h8 = hi*8;

  float sy = (y+0.5f)*0.125f - 0.5f;
  int iy = (int)floorf(sy); float fy = sy - (float)iy;
  int ya = min(max(iy,0),15), yb = min(max(iy+1,0),15);

  for (int idx=t; idx<1024; idx+=256){
    int c = idx>>4, xq = idx&15;
    f4 v = *(const f4*)(hn + ((((size_t)b*64+c)*HSZ + y)*WSZ + x0 + xq*4));
    float* d = &rowF[c*69 + xq*4];
    d[0]=v[0]; d[1]=v[1]; d[2]=v[2]; d[3]=v[3];
  }
  for (int idx=t; idx<1536; idx+=256){
    int cp = idx>>3, rr = (idx>>2)&1, q = idx&3;
    int ry = rr? yb : ya;
    f4 v = *(const f4*)(Cs + (((size_t)b*192 + cp)*256 + ry*16 + q*4));
    *(f4*)&CsL[cp*36 + rr*16 + q*4] = v;
  }
  __syncthreads();

  bf16x8 bfr[2];
  #pragma unroll
  for (int ks=0; ks<2; ks++){
    union { bf16x8 v; __hip_bfloat16 e[8]; } u;
    #pragma unroll
    for (int j=0;j<8;j++)
      u.e[j] = __float2bfloat16(rowF[(ks*32 + h8 + j)*69 + w*16 + ln15]);
    bfr[ks] = u.v;
  }
  f32x4 acc[12];
  #pragma unroll
  for (int mt=0;mt<12;mt++) acc[mt] = (f32x4){0.f,0.f,0.f,0.f};
  #pragma unroll
  for (int ks=0; ks<2; ks++){
    #pragma unroll
    for (int mt=0; mt<12; mt++){
      bf16x8 af = *(const bf16x8*)(WhB + ((mt*16+ln15)*64 + ks*32 + h8));
      acc[mt] = __builtin_amdgcn_mfma_f32_16x16x32_bf16(af, bfr[ks], acc[mt], 0, 0, 0);
    }
  }

  int xg = x0 + w*16 + ln15;
  float sx = (xg+0.5f)*0.125f - 0.5f;
  int ix = (int)floorf(sx); float fx = sx - (float)ix;
  int xa = min(max(ix,0),15), xb2 = min(max(ix+1,0),15);
  float w00=(1.f-fy)*(1.f-fx), w01=(1.f-fy)*fx, w10=fy*(1.f-fx), w11=fy*fx;
  int o00 = xa, o01 = xb2, o10 = 16+xa, o11 = 16+xb2;
  #pragma unroll
  for (int mt=0; mt<4; mt++){
    #pragma unroll
    for (int r=0; r<4; r++){
      int c = mt*16 + hi*4 + r;
      const float* p0 = &CsL[c*36];
      const float* p1 = &CsL[(64+c)*36];
      const float* p2 = &CsL[(128+c)*36];
      float vo = acc[mt][r]   + p0[o00]*w00 + p0[o01]*w01 + p0[o10]*w10 + p0[o11]*w11 + bcv[c];
      float vg = acc[mt+4][r] + p1[o00]*w00 + p1[o01]*w01 + p1[o10]*w10 + p1[o11]*w11 + bcv[64+c];
      float vi = acc[mt+8][r] + p2[o00]*w00 + p2[o01]*w01 + p2[o10]*w10 + p2[o11]*w11 + bcv[128+c];
      size_t pix = (((size_t)b*64+c)*HSZ + y)*WSZ + xg;
      float mv = m_in[pix];
      float smi = sigm(vi);
      float nm = (1.f-smi)*mv + smi*tanh_fast(vg);
      float nh = sigm(vo)*nm;
      out_h[pix] = nh;
      out_m[pix] = nm;
    }
  }
}

extern "C" void kernel_launch(void* const* d_in, const int* in_sizes, int n_in,
                              void* d_out, int out_size, void* d_ws, size_t ws_size,
                              hipStream_t stream){
  (void)in_sizes; (void)n_in; (void)out_size;
  const float* x    = (const float*)d_in[0];
  const float* cst  = (const float*)d_in[1];
  const float* h    = (const float*)d_in[2];
  const float* m    = (const float*)d_in[3];
  const float* conv_w = (const float*)d_in[4];
  // d_in[5] conv_b: exactly cancelled by instance norm — unused
  const float* gn_w = (const float*)d_in[6];
  const float* gn_b = (const float*)d_in[7];
  const float* qh_w = (const float*)d_in[8];  const float* qh_b = (const float*)d_in[9];
  const float* kh_w = (const float*)d_in[10]; const float* kh_b = (const float*)d_in[11];
  const float* vh_w = (const float*)d_in[12]; const float* vh_b = (const float*)d_in[13];
  const float* km_w = (const float*)d_in[14]; const float* km_b = (const float*)d_in[15];
  const float* vm_w = (const float*)d_in[16]; const float* vm_b = (const float*)d_in[17];
  const float* z_w  = (const float*)d_in[18]; const float* z_b  = (const float*)d_in[19];
  const float* m_w  = (const float*)d_in[20]; const float* m_b  = (const float*)d_in[21];

  float* out   = (float*)d_out;
  float* out_h = out;                        // doubles as h_next scratch
  float* out_c = out + 16777216;
  float* out_m = out + 33554432;

  char* ws = (char*)d_ws;
  // region A: cc (bf16, 134,217,728 B); aliased AFTER k_gate by attention scratch
  __hip_bfloat16* cc = (__hip_bfloat16*)ws;
  float* proj = (float*)(ws + 2097152);              //  5,242,880 B (alias cc, post-gate)
  float* Amat = (float*)(ws + 7340032);              //  8,388,608 B
  float* Zcat = (float*)(ws + 15728640);             //  2,097,152 B
  float* Cs   = (float*)(ws + 17825792);             //  3,145,728 B (ends 20,971,520)
  float* pool = (float*)(ws + 134217728);            // 2,097,152 B — aliases im region, post-conv

  // big path: im holds all 16 batches (67 MB); weights region relocated past it.
  bool big = (ws_size >= (size_t)202200000);
  size_t imOff = 134217728;
  size_t wOff  = big ? (imOff + 67108864) : 150994944;
  __hip_bfloat16* im  = (__hip_bfloat16*)(ws + imOff);
  __hip_bfloat16* wB  = (__hip_bfloat16*)(ws + wOff);                 //   589,824 B
  __hip_bfloat16* WhB = (__hip_bfloat16*)(ws + wOff +  589824);       //    24,576 B
  float* W2   = (float*)(ws + wOff +  614400);                        //    98,304 B
  float* bcv  = (float*)(ws + wOff +  712704);                        //       768 B
  float* gnsc = (float*)(ws + wOff +  713472);                        //    16,384 B
  float* gnsh = (float*)(ws + wOff +  729856);                        //    16,384 B

  hipLaunchKernelGGL(k_setup, dim3(1297), dim3(256), 0, stream,
                     conv_w, m_w, z_w, z_b, m_b, wB, WhB, W2, bcv);
  if (big){
    hipLaunchKernelGGL(k_im,   dim3(2048),    dim3(256), 0, stream, x, h, im, 0);
    hipLaunchKernelGGL(k_conv, dim3(2048, 2), dim3(256), 0, stream, im, wB, cc, 0);
  } else {
    for (int q = 0; q < 4; q++){
      hipLaunchKernelGGL(k_im,   dim3(512),    dim3(256), 0, stream, x, h, im, q*4);
      hipLaunchKernelGGL(k_conv, dim3(512, 2), dim3(256), 0, stream, im, wB, cc, q*4);
    }
  }
  hipLaunchKernelGGL(k_gnstats, dim3(4096), dim3(256), 0, stream, cc, gn_w, gn_b, gnsc, gnsh);
  hipLaunchKernelGGL(k_gate, dim3(1024), dim3(256), 0, stream, cc, cst, gnsc, gnsh, out_c, out_h, pool);
  hipLaunchKernelGGL(k_poolm, dim3(1024), dim3(256), 0, stream, m, pool + 262144);
  hipLaunchKernelGGL(k_proj, dim3(80), dim3(256), 0, stream, pool,
                     qh_w,qh_b,kh_w,kh_b,vh_w,vh_b,km_w,km_b,vm_w,vm_b, proj);
  hipLaunchKernelGGL(k_scores, dim3(256,2,16), dim3(256), 0, stream, proj, Amat);
  hipLaunchKernelGGL(k_apply, dim3(2,16,4), dim3(256), 0, stream, proj, Amat, Zcat);
  hipLaunchKernelGGL(k_csmall, dim3(6,16), dim3(256), 0, stream, Zcat, W2, Cs);
  hipLaunchKernelGGL(k_final, dim3(4096), dim3(256), 0, stream, out_h, m, WhB, Cs, bcv, out_h, out_m);
}